// Round 1
// baseline (188.833 us; speedup 1.0000x reference)
//
#include <hip/hip_runtime.h>

// QuantizedBatchNorm (k=8 fake-quant, training forward), NCHW = [64,256,56,56] f32.
//
// Schedule (deterministic, no atomics):
//  P1: read x -> per-(channel,split) partial {sum, min, max}
//  S1: 1 block: mean update + quant; derive global amax of (x-mean) from per-ch
//      min/max (monotonicity) -> ctr quant params + per-ch ctr extremes
//  P2: read x -> ctr = Q1(x-mean_c); accumulate sum(ctr^2); store 8-bit level k
//  S2: 1 block: var update + quant, inv_den quant, xn/y quant params from
//      per-channel ctr extremes (monotone chain), quantize weight/bias
//  P3: read k -> reconstruct ctr bit-exactly -> xn=Q3(ctr/inv_den) ->
//      y=Q4(qw*xn+qb) -> write y
// All elementwise math uses __f*_rn to match numpy rounding (no fma contraction).

#define C_CH 256
#define N_B 64
#define HW 3136
#define HW4 784            // HW/4 float4 per plane
#define NHW_F 200704.0f
#define S_SPLIT 16
#define PLANES 4           // N_B / S_SPLIT
#define NCHW 51380224ull

__device__ __forceinline__ float fq(float x, float sc, float qn, float qx) {
  if (sc == 0.0f) return x;                                   // range==0 passthrough
  float cs = __fsub_rn(fminf(fmaxf(x, qn), qx), qn);
  float f  = floorf(__fadd_rn(__fdiv_rn(cs, sc), 0.5f));
  return __fadd_rn(__fmul_rn(f, sc), qn);
}

__device__ __forceinline__ void qparams(float amax, float& sc, float& qn, float& qx) {
  sc = __fdiv_rn(__fmul_rn(2.0f, amax), 255.0f);              // (2*mx)/qmax
  qn = __fmul_rn(-128.0f, sc);                                // -nzp*scale, nzp=round(127.5)=128
  qx = __fmul_rn(127.0f, sc);                                 // (qmax-nzp)*scale
}

__device__ __forceinline__ float block_red_max(float v, float* red) {
  const int t = threadIdx.x;
  red[t] = v; __syncthreads();
  for (int off = 128; off > 0; off >>= 1) {
    if (t < off) red[t] = fmaxf(red[t], red[t + off]);
    __syncthreads();
  }
  float r = red[0];
  __syncthreads();
  return r;
}

// ---------------- P1: per-channel partial sum/min/max ----------------
__global__ __launch_bounds__(256) void k_p1(const float* __restrict__ x,
    float* __restrict__ psum, float* __restrict__ pmin, float* __restrict__ pmax) {
  const int c = blockIdx.x, s = blockIdx.y, t = threadIdx.x;
  float sum = 0.0f, mn = INFINITY, mx = -INFINITY;
  for (int i = 0; i < PLANES; ++i) {
    const int n = s * PLANES + i;
    const float4* p = (const float4*)(x + (size_t)(n * C_CH + c) * HW);
    for (int j = t; j < HW4; j += 256) {
      float4 v = p[j];
      sum = __fadd_rn(sum, __fadd_rn(__fadd_rn(v.x, v.y), __fadd_rn(v.z, v.w)));
      mn = fminf(mn, fminf(fminf(v.x, v.y), fminf(v.z, v.w)));
      mx = fmaxf(mx, fmaxf(fmaxf(v.x, v.y), fmaxf(v.z, v.w)));
    }
  }
  __shared__ float rs[256], rn_[256], rx_[256];
  rs[t] = sum; rn_[t] = mn; rx_[t] = mx; __syncthreads();
  for (int off = 128; off > 0; off >>= 1) {
    if (t < off) {
      rs[t] = __fadd_rn(rs[t], rs[t + off]);
      rn_[t] = fminf(rn_[t], rn_[t + off]);
      rx_[t] = fmaxf(rx_[t], rx_[t + off]);
    }
    __syncthreads();
  }
  if (t == 0) {
    const int idx = c * S_SPLIT + s;
    psum[idx] = rs[0]; pmin[idx] = rn_[0]; pmax[idx] = rx_[0];
  }
}

// ---------------- S1: mean quant + ctr quant params ----------------
__global__ __launch_bounds__(256) void k_s1(const float* __restrict__ psum,
    const float* __restrict__ pmin, const float* __restrict__ pmax,
    const float* __restrict__ run_mean,
    float* __restrict__ meanq, float* __restrict__ ctrmax, float* __restrict__ ctrmin,
    float* __restrict__ scal) {
  __shared__ float red[256];
  const int c = threadIdx.x;
  float sum = 0.0f, mn = INFINITY, mx = -INFINITY;
  for (int s = 0; s < S_SPLIT; ++s) {
    const int idx = c * S_SPLIT + s;
    sum = __fadd_rn(sum, psum[idx]);
    mn = fminf(mn, pmin[idx]);
    mx = fmaxf(mx, pmax[idx]);
  }
  const float new_mean = __fdiv_rn(sum, NHW_F);
  const float mp = __fadd_rn(__fmul_rn(0.875f, run_mean[c]), __fmul_rn(0.125f, new_mean));
  const float am = block_red_max(fabsf(mp), red);
  float scm, qnm, qxm; qparams(am, scm, qnm, qxm);
  const float meanc = fq(mp, scm, qnm, qxm);
  meanq[c] = meanc;
  // (x - mean_c) is monotone in x per channel -> extremes from x extremes (attained)
  const float tmax = __fsub_rn(mx, meanc);
  const float tmin = __fsub_rn(mn, meanc);
  const float a1 = block_red_max(fmaxf(fabsf(tmax), fabsf(tmin)), red);
  float s1v, n1v, x1v; qparams(a1, s1v, n1v, x1v);
  if (c == 0) { scal[0] = s1v; scal[1] = n1v; scal[2] = x1v; }
  ctrmax[c] = fq(tmax, s1v, n1v, x1v);
  ctrmin[c] = fq(tmin, s1v, n1v, x1v);
}

// ---------------- P2: ctr quant levels + sum(ctr^2) ----------------
template<int STORE_K>
__global__ __launch_bounds__(256) void k_p2(const float* __restrict__ x,
    const float* __restrict__ meanq, const float* __restrict__ scal,
    unsigned char* __restrict__ kq, float* __restrict__ pss) {
  const int c = blockIdx.x, s = blockIdx.y, t = threadIdx.x;
  const float s1v = scal[0], n1v = scal[1], x1v = scal[2];
  const float m = meanq[c];
  float ss = 0.0f;
  for (int i = 0; i < PLANES; ++i) {
    const size_t base = (size_t)((s * PLANES + i) * C_CH + c) * HW;
    const float4* p = (const float4*)(x + base);
    uchar4* kp = (uchar4*)(kq + base);
    for (int j = t; j < HW4; j += 256) {
      float4 v = p[j];
      float vv[4] = {v.x, v.y, v.z, v.w};
      unsigned char kb[4];
      #pragma unroll
      for (int e = 0; e < 4; ++e) {
        const float tt = __fsub_rn(vv[e], m);
        const float cs = __fsub_rn(fminf(fmaxf(tt, n1v), x1v), n1v);
        const float f = floorf(__fadd_rn(__fdiv_rn(cs, s1v), 0.5f));
        const float ctr = __fadd_rn(__fmul_rn(f, s1v), n1v);
        ss = __fadd_rn(ss, __fmul_rn(ctr, ctr));
        kb[e] = (unsigned char)f;                 // f in [0,255] by construction
      }
      if (STORE_K) {
        uchar4 kk; kk.x = kb[0]; kk.y = kb[1]; kk.z = kb[2]; kk.w = kb[3];
        kp[j] = kk;
      }
    }
  }
  __shared__ float red[256];
  red[t] = ss; __syncthreads();
  for (int off = 128; off > 0; off >>= 1) {
    if (t < off) red[t] = __fadd_rn(red[t], red[t + off]);
    __syncthreads();
  }
  if (t == 0) pss[c * S_SPLIT + s] = red[0];
}

// ---------------- S2: var/inv_den quant, xn/y quant params, qw/qb ----------------
__global__ __launch_bounds__(256) void k_s2(const float* __restrict__ pss,
    const float* __restrict__ run_var, const float* __restrict__ ctrmax,
    const float* __restrict__ ctrmin, const float* __restrict__ weight,
    const float* __restrict__ bias,
    float* __restrict__ invden, float* __restrict__ qwv, float* __restrict__ qbv,
    float* __restrict__ scal) {
  __shared__ float red[256];
  const int c = threadIdx.x;
  float ss = 0.0f;
  for (int s = 0; s < S_SPLIT; ++s) ss = __fadd_rn(ss, pss[c * S_SPLIT + s]);
  const float new_var = __fdiv_rn(ss, NHW_F);
  const float vp = __fadd_rn(__fmul_rn(0.875f, run_var[c]), __fmul_rn(0.125f, new_var));
  const float av = block_red_max(fabsf(vp), red);
  float scv, qnv, qxv; qparams(av, scv, qnv, qxv);
  const float varc = fq(vp, scv, qnv, qxv);
  const float dp = __fsqrt_rn(__fadd_rn(varc, 1e-5f));
  const float ad = block_red_max(fabsf(dp), red);
  float scd, qnd, qxd; qparams(ad, scd, qnd, qxd);
  const float idc = fq(dp, scd, qnd, qxd);
  invden[c] = idc;
  // xn_pre = ctr / idc monotone (idc>0): extremes attained at ctr extremes
  const float xpmax = __fdiv_rn(ctrmax[c], idc);
  const float xpmin = __fdiv_rn(ctrmin[c], idc);
  const float a3 = block_red_max(fmaxf(fabsf(xpmax), fabsf(xpmin)), red);
  float s3v, n3v, x3v; qparams(a3, s3v, n3v, x3v);
  const float xnmax = fq(xpmax, s3v, n3v, x3v);
  const float xnmin = fq(xpmin, s3v, n3v, x3v);
  const float wv = weight[c];
  const float aw = block_red_max(fabsf(wv), red);
  float scw, qnw, qxw; qparams(aw, scw, qnw, qxw);
  const float qw = fq(wv, scw, qnw, qxw); qwv[c] = qw;
  const float bv = bias[c];
  const float ab = block_red_max(fabsf(bv), red);
  float scb, qnb, qxb; qparams(ab, scb, qnb, qxb);
  const float qb = fq(bv, scb, qnb, qxb); qbv[c] = qb;
  // y_pre = qw*xn + qb affine-monotone in xn: extremes at xn endpoints (attained)
  const float e1 = __fadd_rn(__fmul_rn(qw, xnmax), qb);
  const float e2 = __fadd_rn(__fmul_rn(qw, xnmin), qb);
  const float a4 = block_red_max(fmaxf(fabsf(e1), fabsf(e2)), red);
  float s4v, n4v, x4v; qparams(a4, s4v, n4v, x4v);
  if (c == 0) {
    scal[3] = s3v; scal[4] = n3v; scal[5] = x3v;
    scal[6] = s4v; scal[7] = n4v; scal[8] = x4v;
  }
}

// ---------------- P3 (k path): reconstruct ctr from uint8 level ----------------
__global__ __launch_bounds__(256) void k_p3_k(const unsigned char* __restrict__ kq,
    const float* __restrict__ invden, const float* __restrict__ qwv,
    const float* __restrict__ qbv, const float* __restrict__ scal,
    float* __restrict__ y) {
  const int c = blockIdx.x, s = blockIdx.y, t = threadIdx.x;
  const float s1v = scal[0], n1v = scal[1];
  const float s3v = scal[3], n3v = scal[4], x3v = scal[5];
  const float s4v = scal[6], n4v = scal[7], x4v = scal[8];
  const float id = invden[c], w = qwv[c], b = qbv[c];
  for (int i = 0; i < PLANES; ++i) {
    const size_t base = (size_t)((s * PLANES + i) * C_CH + c) * HW;
    const uchar4* kp = (const uchar4*)(kq + base);
    float4* yp = (float4*)(y + base);
    for (int j = t; j < HW4; j += 256) {
      const uchar4 kk = kp[j];
      const unsigned char ka[4] = {kk.x, kk.y, kk.z, kk.w};
      float out[4];
      #pragma unroll
      for (int e = 0; e < 4; ++e) {
        const float ctr = __fadd_rn(__fmul_rn((float)ka[e], s1v), n1v); // == floor(..)*s+nmin bit-exact
        const float xn = fq(__fdiv_rn(ctr, id), s3v, n3v, x3v);
        out[e] = fq(__fadd_rn(__fmul_rn(w, xn), b), s4v, n4v, x4v);
      }
      float4 o; o.x = out[0]; o.y = out[1]; o.z = out[2]; o.w = out[3];
      yp[j] = o;
    }
  }
}

// ---------------- P3 (x path fallback, if ws too small for k) ----------------
__global__ __launch_bounds__(256) void k_p3_x(const float* __restrict__ x,
    const float* __restrict__ meanq,
    const float* __restrict__ invden, const float* __restrict__ qwv,
    const float* __restrict__ qbv, const float* __restrict__ scal,
    float* __restrict__ y) {
  const int c = blockIdx.x, s = blockIdx.y, t = threadIdx.x;
  const float s1v = scal[0], n1v = scal[1], x1v = scal[2];
  const float s3v = scal[3], n3v = scal[4], x3v = scal[5];
  const float s4v = scal[6], n4v = scal[7], x4v = scal[8];
  const float m = meanq[c], id = invden[c], w = qwv[c], b = qbv[c];
  for (int i = 0; i < PLANES; ++i) {
    const size_t base = (size_t)((s * PLANES + i) * C_CH + c) * HW;
    const float4* p = (const float4*)(x + base);
    float4* yp = (float4*)(y + base);
    for (int j = t; j < HW4; j += 256) {
      float4 v = p[j];
      float vv[4] = {v.x, v.y, v.z, v.w};
      float out[4];
      #pragma unroll
      for (int e = 0; e < 4; ++e) {
        const float tt = __fsub_rn(vv[e], m);
        const float ctr = fq(tt, s1v, n1v, x1v);
        const float xn = fq(__fdiv_rn(ctr, id), s3v, n3v, x3v);
        out[e] = fq(__fadd_rn(__fmul_rn(w, xn), b), s4v, n4v, x4v);
      }
      float4 o; o.x = out[0]; o.y = out[1]; o.z = out[2]; o.w = out[3];
      yp[j] = o;
    }
  }
}

extern "C" void kernel_launch(void* const* d_in, const int* in_sizes, int n_in,
                              void* d_out, int out_size, void* d_ws, size_t ws_size,
                              hipStream_t stream) {
  const float* x        = (const float*)d_in[0];
  const float* weight   = (const float*)d_in[1];
  const float* bias     = (const float*)d_in[2];
  const float* run_mean = (const float*)d_in[3];
  const float* run_var  = (const float*)d_in[4];
  float* y = (float*)d_out;

  float* w = (float*)d_ws;
  float* psum   = w;               // 4096
  float* pmin   = w + 4096;        // 4096
  float* pmax   = w + 8192;        // 4096
  float* pss    = w + 12288;       // 4096
  float* meanq  = w + 16384;       // 256
  float* ctrmax = w + 16640;       // 256
  float* ctrmin = w + 16896;       // 256
  float* invden = w + 17152;       // 256
  float* qwv    = w + 17408;       // 256
  float* qbv    = w + 17664;       // 256
  float* scal   = w + 17920;       // 16
  unsigned char* kq = (unsigned char*)d_ws + 73728;  // 51,380,224 bytes
  const size_t need_k = 73728ull + NCHW;
  const bool use_k = (ws_size >= need_k);

  dim3 grid(C_CH, S_SPLIT), blk(256);
  k_p1<<<grid, blk, 0, stream>>>(x, psum, pmin, pmax);
  k_s1<<<1, 256, 0, stream>>>(psum, pmin, pmax, run_mean, meanq, ctrmax, ctrmin, scal);
  if (use_k) k_p2<1><<<grid, blk, 0, stream>>>(x, meanq, scal, kq, pss);
  else       k_p2<0><<<grid, blk, 0, stream>>>(x, meanq, scal, kq, pss);
  k_s2<<<1, 256, 0, stream>>>(pss, run_var, ctrmax, ctrmin, weight, bias,
                              invden, qwv, qbv, scal);
  if (use_k) k_p3_k<<<grid, blk, 0, stream>>>(kq, invden, qwv, qbv, scal, y);
  else       k_p3_x<<<grid, blk, 0, stream>>>(x, meanq, invden, qwv, qbv, scal, y);
}

// Round 2
// 181.287 us; speedup vs baseline: 1.0416x; 1.0416x over previous
//
#include <hip/hip_runtime.h>
#include <stdint.h>

// QuantizedBatchNorm (k=8 fake-quant, training forward), NCHW = [64,256,56,56] f32.
//
// 3-kernel schedule (deterministic, no atomics):
//  K1: read x -> per-(channel,split) partial {sum, min, max}   (1024 blocks = 256ch x 4)
//  K2: prologue = redundant S1 per block (mean quant + ctr quant params from
//      per-channel min/max via monotonicity); main = read x, compute 8-bit quant
//      level k, store packed 16 levels/uint4, accumulate sum(ctr^2)
//  K3: prologue = redundant S1+S2 (var/inv_den quant, xn/y quant params from
//      attained per-channel extremes, qw/qb) + build 256-entry per-channel y-LUT
//      in LDS (bit-exact __fdiv_rn math, once per block); main = read k, y = lut[k]
// All elementwise math uses __f*_rn (no fma contraction) to match numpy rounding.

#define C_CH 256
#define HW 3136
#define P4 784            // float4 slots per plane
#define P16 196           // uint4 (16-elem) slots per plane
#define NHW_F 200704.0f
#define NCHW 51380224ull

__device__ __forceinline__ float fq(float x, float sc, float qn, float qx) {
  if (sc == 0.0f) return x;                                   // range==0 passthrough
  float cs = __fsub_rn(fminf(fmaxf(x, qn), qx), qn);
  float f  = floorf(__fadd_rn(__fdiv_rn(cs, sc), 0.5f));
  return __fadd_rn(__fmul_rn(f, sc), qn);
}

__device__ __forceinline__ void qparams(float amax, float& sc, float& qn, float& qx) {
  sc = __fdiv_rn(__fmul_rn(2.0f, amax), 255.0f);              // (2*mx)/qmax
  qn = __fmul_rn(-128.0f, sc);                                // -nzp*scale, nzp=round(127.5)=128
  qx = __fmul_rn(127.0f, sc);                                 // (qmax-nzp)*scale
}

// block = 256 threads = 4 waves. Deterministic wave butterfly + fixed-order combine.
__device__ __forceinline__ float block_max(float v, float* buf4) {
  #pragma unroll
  for (int m = 1; m <= 32; m <<= 1) v = fmaxf(v, __shfl_xor(v, m, 64));
  if ((threadIdx.x & 63) == 0) buf4[threadIdx.x >> 6] = v;
  __syncthreads();
  float r = fmaxf(fmaxf(buf4[0], buf4[1]), fmaxf(buf4[2], buf4[3]));
  __syncthreads();
  return r;
}

__device__ __forceinline__ float block_sum(float v, float* buf4) {
  #pragma unroll
  for (int m = 1; m <= 32; m <<= 1) v = __fadd_rn(v, __shfl_xor(v, m, 64));
  if ((threadIdx.x & 63) == 0) buf4[threadIdx.x >> 6] = v;
  __syncthreads();
  float r = __fadd_rn(__fadd_rn(__fadd_rn(buf4[0], buf4[1]), buf4[2]), buf4[3]);
  __syncthreads();
  return r;
}

// Redundant S1: thread t <-> channel t. Deterministic, identical in every block.
struct S1Out { float meanc, tmax, tmin, s1, n1, x1; };

__device__ __forceinline__ void s1_compute(const float* __restrict__ psum,
    const float* __restrict__ pmin, const float* __restrict__ pmax,
    const float* __restrict__ run_mean, float* buf4, S1Out& o) {
  const int t = threadIdx.x;
  float sum = __fadd_rn(__fadd_rn(__fadd_rn(psum[4*t], psum[4*t+1]), psum[4*t+2]), psum[4*t+3]);
  float mn = fminf(fminf(pmin[4*t], pmin[4*t+1]), fminf(pmin[4*t+2], pmin[4*t+3]));
  float mx = fmaxf(fmaxf(pmax[4*t], pmax[4*t+1]), fmaxf(pmax[4*t+2], pmax[4*t+3]));
  const float new_mean = __fdiv_rn(sum, NHW_F);
  const float mp = __fadd_rn(__fmul_rn(0.875f, run_mean[t]), __fmul_rn(0.125f, new_mean));
  const float am = block_max(fabsf(mp), buf4);
  float scm, qnm, qxm; qparams(am, scm, qnm, qxm);
  o.meanc = fq(mp, scm, qnm, qxm);
  o.tmax = __fsub_rn(mx, o.meanc);   // extremes of (x - mean_c): attained, monotone in x
  o.tmin = __fsub_rn(mn, o.meanc);
  const float a1 = block_max(fmaxf(fabsf(o.tmax), fabsf(o.tmin)), buf4);
  qparams(a1, o.s1, o.n1, o.x1);
}

// ---------------- K1: per-channel partial sum/min/max ----------------
__global__ __launch_bounds__(256) void k_p1(const float4* __restrict__ x4,
    float* __restrict__ psum, float* __restrict__ pmin, float* __restrict__ pmax) {
  const int c = blockIdx.x, s = blockIdx.y, t = threadIdx.x;
  float sum = 0.0f, mn = INFINITY, mx = -INFINITY;
  #pragma unroll 4
  for (int mm = 0; mm < 12; ++mm) {
    const int u = t + 256 * mm;
    const int plane = u / P16, off4 = u - plane * P16;
    const float4* p = x4 + (size_t)((s * 16 + plane) * C_CH + c) * P4 + 4 * (size_t)off4;
    #pragma unroll
    for (int q = 0; q < 4; ++q) {
      float4 v = p[q];
      sum = __fadd_rn(sum, __fadd_rn(__fadd_rn(v.x, v.y), __fadd_rn(v.z, v.w)));
      mn = fminf(mn, fminf(fminf(v.x, v.y), fminf(v.z, v.w)));
      mx = fmaxf(mx, fmaxf(fmaxf(v.x, v.y), fmaxf(v.z, v.w)));
    }
  }
  { // tail: plane 15, float4 slots 528..783
    float4 v = x4[(size_t)((s * 16 + 15) * C_CH + c) * P4 + 528 + t];
    sum = __fadd_rn(sum, __fadd_rn(__fadd_rn(v.x, v.y), __fadd_rn(v.z, v.w)));
    mn = fminf(mn, fminf(fminf(v.x, v.y), fminf(v.z, v.w)));
    mx = fmaxf(mx, fmaxf(fmaxf(v.x, v.y), fmaxf(v.z, v.w)));
  }
  __shared__ float buf4[4];
  const float bs = block_sum(sum, buf4);
  // min via max of negation to reuse helper
  const float bmx = block_max(mx, buf4);
  const float bmn = -block_max(-mn, buf4);
  if (t == 0) {
    const int idx = c * 4 + s;
    psum[idx] = bs; pmin[idx] = bmn; pmax[idx] = bmx;
  }
}

// ---------------- K2: S1 prologue + ctr levels + sum(ctr^2) ----------------
template<int STORE_K>
__global__ __launch_bounds__(256) void k_p2(const float4* __restrict__ x4,
    uint32_t* __restrict__ kq,
    const float* __restrict__ psum, const float* __restrict__ pmin,
    const float* __restrict__ pmax, const float* __restrict__ run_mean,
    float* __restrict__ pss) {
  __shared__ float buf4[4];
  __shared__ float bcast[1];
  const int c = blockIdx.x, s = blockIdx.y, t = threadIdx.x;
  S1Out o; s1_compute(psum, pmin, pmax, run_mean, buf4, o);
  if (t == c) bcast[0] = o.meanc;
  __syncthreads();
  const float m_c = bcast[0];
  const float s1 = o.s1, n1 = o.n1, x1 = o.x1;
  float ss = 0.0f;
  #pragma unroll 2
  for (int mm = 0; mm < 12; ++mm) {
    const int u = t + 256 * mm;
    const int plane = u / P16, off4 = u - plane * P16;
    const size_t pb = (size_t)((s * 16 + plane) * C_CH + c);
    const float4* p = x4 + pb * P4 + 4 * (size_t)off4;
    uint32_t kk[4];
    #pragma unroll
    for (int q = 0; q < 4; ++q) {
      float4 v = p[q];
      float vv[4] = {v.x, v.y, v.z, v.w};
      uint32_t kw = 0;
      #pragma unroll
      for (int e = 0; e < 4; ++e) {
        const float tt = __fsub_rn(vv[e], m_c);
        const float cs = __fsub_rn(fminf(fmaxf(tt, n1), x1), n1);
        const float f = floorf(__fadd_rn(__fdiv_rn(cs, s1), 0.5f));
        const float ctr = __fadd_rn(__fmul_rn(f, s1), n1);
        ss = __fadd_rn(ss, __fmul_rn(ctr, ctr));
        kw |= ((uint32_t)f) << (8 * e);
      }
      kk[q] = kw;
    }
    if (STORE_K) {
      uint4 st; st.x = kk[0]; st.y = kk[1]; st.z = kk[2]; st.w = kk[3];
      ((uint4*)kq)[pb * P16 + off4] = st;
    }
  }
  { // tail: plane 15, float4 slots 528..783 -> one u32 of 4 levels
    const size_t pb = (size_t)((s * 16 + 15) * C_CH + c);
    float4 v = x4[pb * P4 + 528 + t];
    float vv[4] = {v.x, v.y, v.z, v.w};
    uint32_t kw = 0;
    #pragma unroll
    for (int e = 0; e < 4; ++e) {
      const float tt = __fsub_rn(vv[e], m_c);
      const float cs = __fsub_rn(fminf(fmaxf(tt, n1), x1), n1);
      const float f = floorf(__fadd_rn(__fdiv_rn(cs, s1), 0.5f));
      const float ctr = __fadd_rn(__fmul_rn(f, s1), n1);
      ss = __fadd_rn(ss, __fmul_rn(ctr, ctr));
      kw |= ((uint32_t)f) << (8 * e);
    }
    if (STORE_K) kq[pb * P4 + 528 + t] = kw;
  }
  const float bss = block_sum(ss, buf4);
  if (t == 0) pss[c * 4 + s] = bss;
}

// ---------------- K3: S1+S2 prologue + per-channel y-LUT + gather ----------------
template<int USE_K>
__global__ __launch_bounds__(256) void k_p3(const float4* __restrict__ x4,
    const uint32_t* __restrict__ kq,
    const float* __restrict__ psum, const float* __restrict__ pmin,
    const float* __restrict__ pmax, const float* __restrict__ pss,
    const float* __restrict__ run_mean, const float* __restrict__ run_var,
    const float* __restrict__ weight, const float* __restrict__ bias,
    float4* __restrict__ y4) {
  __shared__ float buf4[4];
  __shared__ float bcast[4];
  __shared__ float lutL[256];
  const int c = blockIdx.x, s = blockIdx.y, t = threadIdx.x;
  S1Out o; s1_compute(psum, pmin, pmax, run_mean, buf4, o);
  // S2 (thread t <-> channel t), identical in every block:
  float ssq = __fadd_rn(__fadd_rn(__fadd_rn(pss[4*t], pss[4*t+1]), pss[4*t+2]), pss[4*t+3]);
  const float new_var = __fdiv_rn(ssq, NHW_F);
  const float vp = __fadd_rn(__fmul_rn(0.875f, run_var[t]), __fmul_rn(0.125f, new_var));
  const float av = block_max(fabsf(vp), buf4);
  float scv, qnv, qxv; qparams(av, scv, qnv, qxv);
  const float varc = fq(vp, scv, qnv, qxv);
  const float dp = __fsqrt_rn(__fadd_rn(varc, 1e-5f));
  const float ad = block_max(fabsf(dp), buf4);
  float scd, qnd, qxd; qparams(ad, scd, qnd, qxd);
  const float idc = fq(dp, scd, qnd, qxd);
  const float ctrmax = fq(o.tmax, o.s1, o.n1, o.x1);
  const float ctrmin = fq(o.tmin, o.s1, o.n1, o.x1);
  const float xpmax = __fdiv_rn(ctrmax, idc);
  const float xpmin = __fdiv_rn(ctrmin, idc);
  const float a3 = block_max(fmaxf(fabsf(xpmax), fabsf(xpmin)), buf4);
  float s3, n3, x3; qparams(a3, s3, n3, x3);
  const float xnmax = fq(xpmax, s3, n3, x3);
  const float xnmin = fq(xpmin, s3, n3, x3);
  const float wv = weight[t];
  const float aw = block_max(fabsf(wv), buf4);
  float scw, qnw, qxw; qparams(aw, scw, qnw, qxw);
  const float qw = fq(wv, scw, qnw, qxw);
  const float bv = bias[t];
  const float ab = block_max(fabsf(bv), buf4);
  float scb, qnb, qxb; qparams(ab, scb, qnb, qxb);
  const float qb = fq(bv, scb, qnb, qxb);                     // bias==0 -> passthrough
  const float e1 = __fadd_rn(__fmul_rn(qw, xnmax), qb);
  const float e2 = __fadd_rn(__fmul_rn(qw, xnmin), qb);
  const float a4 = block_max(fmaxf(fabsf(e1), fabsf(e2)), buf4);
  float s4, n4, x4p; qparams(a4, s4, n4, x4p);
  if (t == c) { bcast[0] = idc; bcast[1] = qw; bcast[2] = qb; bcast[3] = o.meanc; }
  __syncthreads();
  const float idc_c = bcast[0], qw_c = bcast[1], qb_c = bcast[2], m_c = bcast[3];
  // y-LUT for this block's channel: bit-exact chain per level t
  {
    const float ctr_t = __fadd_rn(__fmul_rn((float)t, o.s1), o.n1);
    const float xn_t = fq(__fdiv_rn(ctr_t, idc_c), s3, n3, x3);
    lutL[t] = fq(__fadd_rn(__fmul_rn(qw_c, xn_t), qb_c), s4, n4, x4p);
  }
  __syncthreads();

  if (USE_K) {
    #pragma unroll 4
    for (int mm = 0; mm < 12; ++mm) {
      const int u = t + 256 * mm;
      const int plane = u / P16, off4 = u - plane * P16;
      const size_t pb = (size_t)((s * 16 + plane) * C_CH + c);
      const uint4 kk = ((const uint4*)kq)[pb * P16 + off4];
      float4* yp = y4 + pb * P4 + 4 * (size_t)off4;
      const uint32_t ka[4] = {kk.x, kk.y, kk.z, kk.w};
      #pragma unroll
      for (int q = 0; q < 4; ++q) {
        const uint32_t w = ka[q];
        float4 o4;
        o4.x = lutL[w & 255]; o4.y = lutL[(w >> 8) & 255];
        o4.z = lutL[(w >> 16) & 255]; o4.w = lutL[w >> 24];
        yp[q] = o4;
      }
    }
    { // tail
      const size_t pb = (size_t)((s * 16 + 15) * C_CH + c);
      const uint32_t w = kq[pb * P4 + 528 + t];
      float4 o4;
      o4.x = lutL[w & 255]; o4.y = lutL[(w >> 8) & 255];
      o4.z = lutL[(w >> 16) & 255]; o4.w = lutL[w >> 24];
      y4[pb * P4 + 528 + t] = o4;
    }
  } else {
    // fallback: recompute from x (ws too small for kq)
    #pragma unroll 2
    for (int mm = 0; mm < 13; ++mm) {
      const int u = t + 256 * mm;
      if (mm == 12) {
        const size_t pb = (size_t)((s * 16 + 15) * C_CH + c);
        float4 v = x4[pb * P4 + 528 + t];
        float vv[4] = {v.x, v.y, v.z, v.w}; float ov[4];
        #pragma unroll
        for (int e = 0; e < 4; ++e) {
          const float ctr = fq(__fsub_rn(vv[e], m_c), o.s1, o.n1, o.x1);
          const float xn = fq(__fdiv_rn(ctr, idc_c), s3, n3, x3);
          ov[e] = fq(__fadd_rn(__fmul_rn(qw_c, xn), qb_c), s4, n4, x4p);
        }
        float4 o4; o4.x = ov[0]; o4.y = ov[1]; o4.z = ov[2]; o4.w = ov[3];
        y4[pb * P4 + 528 + t] = o4;
      } else {
        const int plane = u / P16, off4 = u - plane * P16;
        const size_t pb = (size_t)((s * 16 + plane) * C_CH + c);
        const float4* p = x4 + pb * P4 + 4 * (size_t)off4;
        float4* yp = y4 + pb * P4 + 4 * (size_t)off4;
        #pragma unroll
        for (int q = 0; q < 4; ++q) {
          float4 v = p[q];
          float vv[4] = {v.x, v.y, v.z, v.w}; float ov[4];
          #pragma unroll
          for (int e = 0; e < 4; ++e) {
            const float ctr = fq(__fsub_rn(vv[e], m_c), o.s1, o.n1, o.x1);
            const float xn = fq(__fdiv_rn(ctr, idc_c), s3, n3, x3);
            ov[e] = fq(__fadd_rn(__fmul_rn(qw_c, xn), qb_c), s4, n4, x4p);
          }
          float4 o4; o4.x = ov[0]; o4.y = ov[1]; o4.z = ov[2]; o4.w = ov[3];
          yp[q] = o4;
        }
      }
    }
  }
}

extern "C" void kernel_launch(void* const* d_in, const int* in_sizes, int n_in,
                              void* d_out, int out_size, void* d_ws, size_t ws_size,
                              hipStream_t stream) {
  const float4* x4      = (const float4*)d_in[0];
  const float* weight   = (const float*)d_in[1];
  const float* bias     = (const float*)d_in[2];
  const float* run_mean = (const float*)d_in[3];
  const float* run_var  = (const float*)d_in[4];
  float4* y4 = (float4*)d_out;

  float* w = (float*)d_ws;
  float* psum = w;            // 1024
  float* pmin = w + 1024;     // 1024
  float* pmax = w + 2048;     // 1024
  float* pss  = w + 3072;     // 1024
  uint32_t* kq = (uint32_t*)((char*)d_ws + 16384);   // NCHW bytes
  const bool use_k = (ws_size >= 16384ull + NCHW);

  dim3 grid(C_CH, 4), blk(256);
  k_p1<<<grid, blk, 0, stream>>>(x4, psum, pmin, pmax);
  if (use_k) {
    k_p2<1><<<grid, blk, 0, stream>>>(x4, kq, psum, pmin, pmax, run_mean, pss);
    k_p3<1><<<grid, blk, 0, stream>>>(x4, kq, psum, pmin, pmax, pss,
                                      run_mean, run_var, weight, bias, y4);
  } else {
    k_p2<0><<<grid, blk, 0, stream>>>(x4, kq, psum, pmin, pmax, run_mean, pss);
    k_p3<0><<<grid, blk, 0, stream>>>(x4, kq, psum, pmin, pmax, pss,
                                      run_mean, run_var, weight, bias, y4);
  }
}

// Round 4
// 134.571 us; speedup vs baseline: 1.4032x; 1.3472x over previous
//
#include <hip/hip_runtime.h>
#include <stdint.h>

// QuantizedBatchNorm (k=8 fake-quant, training forward), NCHW = [64,256,56,56] f32.
//
// Schedule B (no kq scratch, x read 3x: 1 HBM + 2 L3-resident):
//  K1: read x -> per-(channel,split) partial {sum, min, max}        (256x4 blocks)
//  K2: prologue = redundant S1 (mean quant + ctr quant params); main = read x,
//      compute 8-bit level k via fast fma-quantizer (exact-fallback at rounding
//      boundaries), accumulate EXACT integer {sum k, sum k^2}
//  K3: prologue = S1+S2 (exact var from integer sums, inv_den/xn/y quant params,
//      qw/qb) + 256-entry per-channel y-LUT in LDS; main = read x, k = same fast
//      quantizer, y = lut[k], nontemporal store (keeps x L3-resident)
// All ref-visible elementwise math uses __f*_rn sequences identical to numpy.

#define C_CH 256
#define P4 784                 // float4 per plane (HW/4)
#define PLANE_STRIDE 200704    // float4 stride between planes at fixed c (256*784)
#define NHW_F 200704.0f
#define NHW_D 200704.0
#define TOLB 1e-3f

typedef float natf4 __attribute__((ext_vector_type(4)));  // nontemporal-store-able

__device__ __forceinline__ float fq(float x, float sc, float qn, float qx) {
  if (sc == 0.0f) return x;                                   // range==0 passthrough
  float cs = __fsub_rn(fminf(fmaxf(x, qn), qx), qn);
  float f  = floorf(__fadd_rn(__fdiv_rn(cs, sc), 0.5f));
  return __fadd_rn(__fmul_rn(f, sc), qn);
}

__device__ __forceinline__ void qparams(float amax, float& sc, float& qn, float& qx) {
  sc = __fdiv_rn(__fmul_rn(2.0f, amax), 255.0f);
  qn = __fmul_rn(-128.0f, sc);                                // nzp = round(127.5) = 128
  qx = __fmul_rn(127.0f, sc);
}

__device__ __forceinline__ float block_max(float v, float* buf4) {
  #pragma unroll
  for (int m = 1; m <= 32; m <<= 1) v = fmaxf(v, __shfl_xor(v, m, 64));
  if ((threadIdx.x & 63) == 0) buf4[threadIdx.x >> 6] = v;
  __syncthreads();
  float r = fmaxf(fmaxf(buf4[0], buf4[1]), fmaxf(buf4[2], buf4[3]));
  __syncthreads();
  return r;
}

// Fast quant level: q ~= (x - m - n1)/s1 via fma; exact __fdiv_rn ref-sequence
// fallback when within TOLB of a floor boundary (|fast-true| <= ~1e-4 << TOLB).
__device__ __forceinline__ uint32_t qlevel(float xv, float r2, float c2,
    float m, float s1, float n1, float x1) {
  float q = fmaf(xv, r2, c2);
  q = fminf(fmaxf(q, 0.0f), 255.0f);
  const float qh = __fadd_rn(q, 0.5f);
  float fl = floorf(qh);
  const float d = __fsub_rn(qh, fl);
  if (__builtin_expect(fminf(d, __fsub_rn(1.0f, d)) < TOLB, 0)) {
    const float tt = __fsub_rn(xv, m);
    const float cs = __fsub_rn(fminf(fmaxf(tt, n1), x1), n1);
    fl = floorf(__fadd_rn(__fdiv_rn(cs, s1), 0.5f));
  }
  return (uint32_t)fl;                                        // in [0,255]
}

// Redundant S1 (thread t <-> channel t; identical in every block).
struct S1Out { float meanc, tmax, tmin, s1, n1, x1; };

__device__ __forceinline__ void s1_compute(const float* __restrict__ psum,
    const float* __restrict__ pmin, const float* __restrict__ pmax,
    const float* __restrict__ run_mean, float* buf4, S1Out& o) {
  const int t = threadIdx.x;
  float sum = __fadd_rn(__fadd_rn(__fadd_rn(psum[4*t], psum[4*t+1]), psum[4*t+2]), psum[4*t+3]);
  float mn = fminf(fminf(pmin[4*t], pmin[4*t+1]), fminf(pmin[4*t+2], pmin[4*t+3]));
  float mx = fmaxf(fmaxf(pmax[4*t], pmax[4*t+1]), fmaxf(pmax[4*t+2], pmax[4*t+3]));
  const float new_mean = __fdiv_rn(sum, NHW_F);
  const float mp = __fadd_rn(__fmul_rn(0.875f, run_mean[t]), __fmul_rn(0.125f, new_mean));
  const float am = block_max(fabsf(mp), buf4);
  float scm, qnm, qxm; qparams(am, scm, qnm, qxm);
  o.meanc = fq(mp, scm, qnm, qxm);
  o.tmax = __fsub_rn(mx, o.meanc);   // (x - mean_c) monotone in x: extremes attained
  o.tmin = __fsub_rn(mn, o.meanc);
  const float a1 = block_max(fmaxf(fabsf(o.tmax), fabsf(o.tmin)), buf4);
  qparams(a1, o.s1, o.n1, o.x1);
}

// ---------------- K1: per-channel partial sum/min/max ----------------
__global__ __launch_bounds__(256) void k_p1(const float4* __restrict__ x4,
    float* __restrict__ psum, float* __restrict__ pmin, float* __restrict__ pmax) {
  const int c = blockIdx.x, s = blockIdx.y, t = threadIdx.x;
  const int B0 = (s * 16 * C_CH + c) * P4;
  float sum = 0.0f, mn = INFINITY, mx = -INFINITY;
  #pragma unroll 1
  for (int g = 0; g < 7; ++g) {
    float4 v[7];
    #pragma unroll
    for (int j = 0; j < 7; ++j) {
      const int u = t + 256 * (7 * g + j);
      v[j] = x4[B0 + (u / P4) * PLANE_STRIDE + (u % P4)];
    }
    #pragma unroll
    for (int j = 0; j < 7; ++j) {
      const float4 w = v[j];
      sum = __fadd_rn(sum, __fadd_rn(__fadd_rn(w.x, w.y), __fadd_rn(w.z, w.w)));
      mn = fminf(mn, fminf(fminf(w.x, w.y), fminf(w.z, w.w)));
      mx = fmaxf(mx, fmaxf(fmaxf(w.x, w.y), fmaxf(w.z, w.w)));
    }
  }
  #pragma unroll
  for (int m = 1; m <= 32; m <<= 1) {
    sum = __fadd_rn(sum, __shfl_xor(sum, m, 64));
    mn = fminf(mn, __shfl_xor(mn, m, 64));
    mx = fmaxf(mx, __shfl_xor(mx, m, 64));
  }
  __shared__ float red[12];
  const int w_ = t >> 6;
  if ((t & 63) == 0) { red[w_] = sum; red[4 + w_] = mn; red[8 + w_] = mx; }
  __syncthreads();
  if (t == 0) {
    const int idx = c * 4 + s;
    psum[idx] = __fadd_rn(__fadd_rn(__fadd_rn(red[0], red[1]), red[2]), red[3]);
    pmin[idx] = fminf(fminf(red[4], red[5]), fminf(red[6], red[7]));
    pmax[idx] = fmaxf(fmaxf(red[8], red[9]), fmaxf(red[10], red[11]));
  }
}

// ---------------- K2: S1 prologue + exact integer {sum k, sum k^2} ----------------
__global__ __launch_bounds__(256) void k_p2(const float4* __restrict__ x4,
    const float* __restrict__ psum, const float* __restrict__ pmin,
    const float* __restrict__ pmax, const float* __restrict__ run_mean,
    uint32_t* __restrict__ pk, uint32_t* __restrict__ pk2) {
  __shared__ float buf4[4];
  __shared__ float bc[1];
  const int c = blockIdx.x, s = blockIdx.y, t = threadIdx.x;
  S1Out o; s1_compute(psum, pmin, pmax, run_mean, buf4, o);
  if (t == c) bc[0] = o.meanc;
  __syncthreads();
  const float m_c = bc[0];
  const double rd = 1.0 / (double)o.s1;
  const float r2 = (float)rd;
  const float c2 = (float)((-(double)m_c - (double)o.n1) * rd);
  const int B0 = (s * 16 * C_CH + c) * P4;
  int sk = 0, sk2 = 0;   // per-thread exact: sk<=5e4, sk2<=1.27e7
  #pragma unroll 1
  for (int g = 0; g < 7; ++g) {
    float4 v[7];
    #pragma unroll
    for (int j = 0; j < 7; ++j) {
      const int u = t + 256 * (7 * g + j);
      v[j] = x4[B0 + (u / P4) * PLANE_STRIDE + (u % P4)];
    }
    #pragma unroll
    for (int j = 0; j < 7; ++j) {
      const float4 w = v[j];
      const float vv[4] = {w.x, w.y, w.z, w.w};
      #pragma unroll
      for (int e = 0; e < 4; ++e) {
        const uint32_t k = qlevel(vv[e], r2, c2, m_c, o.s1, o.n1, o.x1);
        sk += (int)k; sk2 += (int)(k * k);
      }
    }
  }
  #pragma unroll
  for (int m = 1; m <= 32; m <<= 1) {   // wave sums: sk2 <= 8.2e8 fits int
    sk += __shfl_xor(sk, m, 64);
    sk2 += __shfl_xor(sk2, m, 64);
  }
  __shared__ uint32_t ired[8];
  const int w_ = t >> 6;
  if ((t & 63) == 0) { ired[w_] = (uint32_t)sk; ired[4 + w_] = (uint32_t)sk2; }
  __syncthreads();
  if (t == 0) {
    const int idx = c * 4 + s;
    pk[idx]  = ired[0] + ired[1] + ired[2] + ired[3];          // <=1.3e7
    pk2[idx] = ired[4] + ired[5] + ired[6] + ired[7];          // <=3.27e9, fits u32
  }
}

// ---------------- K3: S1+S2 prologue + per-channel y-LUT + fast requant ----------------
__global__ __launch_bounds__(256) void k_p3(const float4* __restrict__ x4,
    const float* __restrict__ psum, const float* __restrict__ pmin,
    const float* __restrict__ pmax, const uint32_t* __restrict__ pk,
    const uint32_t* __restrict__ pk2,
    const float* __restrict__ run_mean, const float* __restrict__ run_var,
    const float* __restrict__ weight, const float* __restrict__ bias,
    natf4* __restrict__ y4) {
  __shared__ float buf4[4];
  __shared__ float bc[4];
  __shared__ float lut[256];
  const int c = blockIdx.x, s = blockIdx.y, t = threadIdx.x;
  S1Out o; s1_compute(psum, pmin, pmax, run_mean, buf4, o);
  // S2 (thread t <-> channel t): exact var from integer sums.
  // sum(ctr^2) = s1^2 * sum((k-128)^2) = s1^2 * (sum k^2 - 256 sum k + 16384*N)
  const unsigned long long ssq = (unsigned long long)pk2[4*t] + pk2[4*t+1]
                               + pk2[4*t+2] + pk2[4*t+3];
  const unsigned int skc = pk[4*t] + pk[4*t+1] + pk[4*t+2] + pk[4*t+3];
  const double s1d = (double)o.s1;
  const double sum_ctr2 = s1d * s1d *
      ((double)ssq - 256.0 * (double)skc + 16384.0 * NHW_D);
  const float new_var = (float)(sum_ctr2 / NHW_D);
  const float vp = __fadd_rn(__fmul_rn(0.875f, run_var[t]), __fmul_rn(0.125f, new_var));
  const float av = block_max(fabsf(vp), buf4);
  float scv, qnv, qxv; qparams(av, scv, qnv, qxv);
  const float varc = fq(vp, scv, qnv, qxv);
  const float dp = __fsqrt_rn(__fadd_rn(varc, 1e-5f));
  const float ad = block_max(fabsf(dp), buf4);
  float scd, qnd, qxd; qparams(ad, scd, qnd, qxd);
  const float idc = fq(dp, scd, qnd, qxd);
  const float ctrmax = fq(o.tmax, o.s1, o.n1, o.x1);
  const float ctrmin = fq(o.tmin, o.s1, o.n1, o.x1);
  const float xpmax = __fdiv_rn(ctrmax, idc);
  const float xpmin = __fdiv_rn(ctrmin, idc);
  const float a3 = block_max(fmaxf(fabsf(xpmax), fabsf(xpmin)), buf4);
  float s3, n3, x3; qparams(a3, s3, n3, x3);
  const float xnmax = fq(xpmax, s3, n3, x3);
  const float xnmin = fq(xpmin, s3, n3, x3);
  const float wv = weight[t];
  const float aw = block_max(fabsf(wv), buf4);
  float scw, qnw, qxw; qparams(aw, scw, qnw, qxw);
  const float qw = fq(wv, scw, qnw, qxw);
  const float bv = bias[t];
  const float ab = block_max(fabsf(bv), buf4);
  float scb, qnb, qxb; qparams(ab, scb, qnb, qxb);
  const float qb = fq(bv, scb, qnb, qxb);                     // bias==0 -> passthrough
  const float e1 = __fadd_rn(__fmul_rn(qw, xnmax), qb);
  const float e2 = __fadd_rn(__fmul_rn(qw, xnmin), qb);
  const float a4 = block_max(fmaxf(fabsf(e1), fabsf(e2)), buf4);
  float s4, n4, x4q; qparams(a4, s4, n4, x4q);
  if (t == c) { bc[0] = idc; bc[1] = qw; bc[2] = qb; bc[3] = o.meanc; }
  __syncthreads();
  const float idc_c = bc[0], qw_c = bc[1], qb_c = bc[2], m_c = bc[3];
  // y-LUT for this block's channel: exact ref chain per level t
  {
    const float ctr_t = __fadd_rn(__fmul_rn((float)t, o.s1), o.n1);
    const float xn_t = fq(__fdiv_rn(ctr_t, idc_c), s3, n3, x3);
    lut[t] = fq(__fadd_rn(__fmul_rn(qw_c, xn_t), qb_c), s4, n4, x4q);
  }
  __syncthreads();

  const double rd = 1.0 / (double)o.s1;
  const float r2 = (float)rd;
  const float c2 = (float)((-(double)m_c - (double)o.n1) * rd);
  const int B0 = (s * 16 * C_CH + c) * P4;
  const float4* x4v = (const float4*)x4;
  #pragma unroll 1
  for (int g = 0; g < 7; ++g) {
    float4 v[7]; int idx[7];
    #pragma unroll
    for (int j = 0; j < 7; ++j) {
      const int u = t + 256 * (7 * g + j);
      idx[j] = B0 + (u / P4) * PLANE_STRIDE + (u % P4);
      v[j] = x4v[idx[j]];
    }
    #pragma unroll
    for (int j = 0; j < 7; ++j) {
      const float4 w = v[j];
      natf4 out;
      out.x = lut[qlevel(w.x, r2, c2, m_c, o.s1, o.n1, o.x1)];
      out.y = lut[qlevel(w.y, r2, c2, m_c, o.s1, o.n1, o.x1)];
      out.z = lut[qlevel(w.z, r2, c2, m_c, o.s1, o.n1, o.x1)];
      out.w = lut[qlevel(w.w, r2, c2, m_c, o.s1, o.n1, o.x1)];
      __builtin_nontemporal_store(out, &y4[idx[j]]);          // don't evict x from L3
    }
  }
}

extern "C" void kernel_launch(void* const* d_in, const int* in_sizes, int n_in,
                              void* d_out, int out_size, void* d_ws, size_t ws_size,
                              hipStream_t stream) {
  const float4* x4      = (const float4*)d_in[0];
  const float* weight   = (const float*)d_in[1];
  const float* bias     = (const float*)d_in[2];
  const float* run_mean = (const float*)d_in[3];
  const float* run_var  = (const float*)d_in[4];
  natf4* y4 = (natf4*)d_out;

  float* w = (float*)d_ws;
  float* psum = w;                       // 1024 f32
  float* pmin = w + 1024;                // 1024 f32
  float* pmax = w + 2048;                // 1024 f32
  uint32_t* pk  = (uint32_t*)(w + 3072); // 1024 u32
  uint32_t* pk2 = (uint32_t*)(w + 4096); // 1024 u32

  dim3 grid(C_CH, 4), blk(256);
  k_p1<<<grid, blk, 0, stream>>>(x4, psum, pmin, pmax);
  k_p2<<<grid, blk, 0, stream>>>(x4, psum, pmin, pmax, run_mean, pk, pk2);
  k_p3<<<grid, blk, 0, stream>>>(x4, psum, pmin, pmax, pk, pk2,
                                 run_mean, run_var, weight, bias, y4);
}